// Round 22
// baseline (2736.931 us; speedup 1.0000x reference)
//
#include <hip/hip_runtime.h>
#include <hip/hip_bf16.h>
#include <math.h>
#include <stdint.h>

typedef __hip_bfloat16 bf16;
typedef __attribute__((ext_vector_type(8))) __bf16 bf16x8;
typedef __attribute__((ext_vector_type(4))) float f32x4;

#define HDIM 768
#define MROWS 6144
#define NCHUNK 6
#define WTL 7077888   // elements of transposed weights per layer

__device__ __forceinline__ float bf2f(unsigned int u) {
  union { unsigned int i; float f; } c; c.i = u << 16; return c.f;
}

__device__ __forceinline__ void gload16(const void* g, void* l) {
  __builtin_amdgcn_global_load_lds((const __attribute__((address_space(1))) void*)g,
                                   (__attribute__((address_space(3))) void*)l, 16, 0, 0);
}

// overflow-safe tanh-approx GELU (error ~1e-3 abs)
__device__ __forceinline__ float gelu_f(float v) {
  const float u2 = 1.5957691216057308f * (v + 0.044715f * v * v * v);
  const float e = __expf(u2);
  const float th = 1.f - 2.f / (e + 1.f);
  return 0.5f * v * (1.f + th);
}

// ---------------- weight transpose + f32->bf16 convert, 128x128 tiles ----------------
// Reads: 512B contiguous per 2-lane row-pair group (16x float4 per lane).
// LDS [128][130] f32 (66.5KB, 2 blocks/CU): row stride 130 = +2 banks mod 32;
// transpose-read covers all 32 banks within each row -> conflict-free.
// Writes: 8x uint4 per lane, 256B contiguous transposed row halves.
// 432 tiles per layer: [0,144) Wq/Wk/Wv/Wo (36 each), [144,288) Wi, [288,432) Wo2.
__device__ __forceinline__ void wconv_body128(
    int bid, const float* Wq, const float* Wk, const float* Wv, const float* Wo,
    const float* Wi, const float* Wo2, bf16* wt, float* tile /*[128*130]*/)
{
  const float* src; bf16* dst; int K, N, tIdx;
  if (bid < 144) {
    int m = bid / 36; tIdx = bid % 36; K = 768; N = 768;
    src = (m == 0) ? Wq : (m == 1) ? Wk : (m == 2) ? Wv : Wo;
    dst = wt + (size_t)m * 589824;
  } else if (bid < 288) {
    tIdx = bid - 144; K = 768; N = 3072; src = Wi; dst = wt + 2359296;
  } else {
    tIdx = bid - 288; K = 3072; N = 768; src = Wo2; dst = wt + 4718592;
  }
  const int tilesN = N >> 7;
  const int tn = tIdx % tilesN, tk = tIdx / tilesN;
  const int n0 = tn * 128, k0 = tk * 128;
  const int t = threadIdx.x;
  const int r = t >> 1, h = t & 1;          // row 0..127, half 0..1

  // read phase: src rows k0+r, cols n0+h*64 .. +64
  const float* srow = src + (size_t)(k0 + r) * N + n0 + h * 64;
  float* trow = tile + r * 130 + h * 64;
#pragma unroll
  for (int j = 0; j < 16; ++j) {
    float4 v = *(const float4*)(srow + j * 4);
    trow[j * 4 + 0] = v.x; trow[j * 4 + 1] = v.y;
    trow[j * 4 + 2] = v.z; trow[j * 4 + 3] = v.w;
  }
  __syncthreads();
  // write phase: dst row n0+r, k range k0+h*64 .. +64  (reads tile[k][r])
  bf16* drow = dst + (size_t)(n0 + r) * K + k0 + h * 64;
#pragma unroll
  for (int j = 0; j < 8; ++j) {
    union { bf16 hh[8]; uint4 u; } pk;
#pragma unroll
    for (int e = 0; e < 8; ++e)
      pk.hh[e] = __float2bfloat16(tile[(h * 64 + j * 8 + e) * 130 + r]);
    *(uint4*)(drow + j * 8) = pk.u;
  }
}

__global__ __launch_bounds__(256) void wconv(
    const float* __restrict__ Wq, const float* __restrict__ Wk,
    const float* __restrict__ Wv, const float* __restrict__ Wo,
    const float* __restrict__ Wi, const float* __restrict__ Wo2,
    bf16* __restrict__ wt)
{
  __shared__ float tile[128 * 130];
  wconv_body128(blockIdx.x, Wq, Wk, Wv, Wo, Wi, Wo2, wt, tile);
}

// all 12 layers in one launch: grid 12*432; layer = bid / 432
__global__ __launch_bounds__(256) void wconv_all(
    const float* __restrict__ Wq, const float* __restrict__ Wk,
    const float* __restrict__ Wv, const float* __restrict__ Wo,
    const float* __restrict__ Wi, const float* __restrict__ Wo2,
    bf16* __restrict__ wt_all)
{
  __shared__ float tile[128 * 130];
  const int l = blockIdx.x / 432;
  const int bid = blockIdx.x - l * 432;
  wconv_body128(bid,
                Wq + (size_t)l * 589824, Wk + (size_t)l * 589824,
                Wv + (size_t)l * 589824, Wo + (size_t)l * 589824,
                Wi + (size_t)l * 2359296, Wo2 + (size_t)l * 2359296,
                wt_all + (size_t)l * WTL, tile);
}

// ---------------- GEMM 128x128, 4 waves, BK=32, ring-2 LDS (R12 exact — best) ----
__global__ __launch_bounds__(256, 3) void gemm128(
    const bf16* __restrict__ A, const bf16* __restrict__ Bt,
    void* __restrict__ out, const float* __restrict__ b0,
    const float* __restrict__ b1, const float* __restrict__ b2,
    int gx, int N, int K, int NT, int epi, int nslice)
{
  __shared__ __align__(16) bf16 As[2][4096];
  __shared__ __align__(16) bf16 Bs[2][4096];

  const int nwg = gridDim.x;
  const int wg = blockIdx.x;
  const int L = (wg & 7) * (nwg >> 3) + (wg >> 3);
  const int per = nwg / nslice;
  const int slice = L / per;
  const int Lr = L - slice * per;
  const int bx = Lr % gx, by = Lr / gx;
  const int m0 = by * 128, n0 = bx * 128;
  const int kb0 = slice * (NT << 5);

  const int t = threadIdx.x;
  const int lane = t & 63;
  const int w = t >> 6;
  const int wr = w >> 1, wc = w & 1;
  const int fr = lane & 15;
  const int g = lane >> 4;

  f32x4 acc[4][4];
#pragma unroll
  for (int i = 0; i < 4; ++i)
#pragma unroll
    for (int j = 0; j < 4; ++j) acc[i][j] = (f32x4)0.f;

  const int r0 = t >> 2, q0 = t & 3;
  const int sq = q0 ^ ((r0 >> 1) & 3);
  const bf16* gA0 = A + (size_t)(m0 + r0) * K + kb0 + sq * 8;
  const bf16* gB0 = Bt + (size_t)(n0 + r0) * K + kb0 + sq * 8;
  const int dst0 = t * 16;

  unsigned offA[4], offB[4];
#pragma unroll
  for (int mf = 0; mf < 4; ++mf) {
    const int R = wr * 64 + mf * 16 + fr;
    offA[mf] = (unsigned)((R * 64 + g * 16) ^ (((R >> 1) & 3) << 4));
  }
#pragma unroll
  for (int nf = 0; nf < 4; ++nf) {
    const int R = wc * 64 + nf * 16 + fr;
    offB[nf] = (unsigned)((R * 64 + g * 16) ^ (((R >> 1) & 3) << 4));
  }
  const unsigned ldsA = (unsigned)(uintptr_t)&As[0][0];
  const unsigned ldsB = (unsigned)(uintptr_t)&Bs[0][0];

#define STAGE(KT, RB) {                                                    \
    const bf16* a_ = gA0 + (size_t)(KT) * 32;                              \
    const bf16* b_ = gB0 + (size_t)(KT) * 32;                              \
    gload16(a_,                  (char*)As[RB] + dst0);                    \
    gload16(a_ + (size_t)64 * K, (char*)As[RB] + dst0 + 4096);             \
    gload16(b_,                  (char*)Bs[RB] + dst0);                    \
    gload16(b_ + (size_t)64 * K, (char*)Bs[RB] + dst0 + 4096); }

  STAGE(0, 0)

#define ITER(KT, CUR) {                                                    \
    const int pf_ = ((KT) + 1 < NT) ? (KT) + 1 : (KT);                     \
    STAGE(pf_, (CUR) ^ 1)                                                  \
    asm volatile("s_waitcnt vmcnt(4)" ::: "memory");                       \
    __builtin_amdgcn_s_barrier();                                          \
    bf16x8 af[4], bfr[4];                                                  \
    const unsigned baA_ = ldsA + (CUR) * 8192u;                            \
    const unsigned baB_ = ldsB + (CUR) * 8192u;                            \
    _Pragma("unroll")                                                      \
    for (int mf = 0; mf < 4; ++mf)                                         \
      asm volatile("ds_read_b128 %0, %1" : "=v"(af[mf]) : "v"(baA_ + offA[mf])); \
    _Pragma("unroll")                                                      \
    for (int nf = 0; nf < 4; ++nf)                                         \
      asm volatile("ds_read_b128 %0, %1" : "=v"(bfr[nf]) : "v"(baB_ + offB[nf])); \
    asm volatile("s_waitcnt lgkmcnt(0)" ::: "memory");                     \
    __builtin_amdgcn_sched_barrier(0);                                     \
    __builtin_amdgcn_s_barrier();                                          \
    __builtin_amdgcn_s_setprio(1);                                         \
    _Pragma("unroll")                                                      \
    for (int mf = 0; mf < 4; ++mf)                                         \
      _Pragma("unroll")                                                    \
      for (int nf = 0; nf < 4; ++nf)                                       \
        acc[mf][nf] = __builtin_amdgcn_mfma_f32_16x16x32_bf16(af[mf], bfr[nf], acc[mf][nf], 0, 0, 0); \
    __builtin_amdgcn_s_setprio(0);                                         \
  }

#pragma unroll 1
  for (int kt = 0; kt < NT; kt += 2) {
    ITER(kt, 0)
    ITER(kt + 1, 1)
  }
  asm volatile("s_waitcnt vmcnt(0)" ::: "memory");
#undef ITER
#undef STAGE

  const int rr = (lane >> 4) * 4;
  const int cc0 = lane & 15;
  if (epi == 0) {
    const int mat = n0 / HDIM;
    const float* bias = (mat == 0) ? b0 : (mat == 1) ? b1 : b2;
    const float qs = (mat == 0) ? 0.125f : 1.0f;
    bf16* dst = (bf16*)out + (size_t)mat * MROWS * HDIM;
    const int nl = n0 - mat * HDIM;
#pragma unroll
    for (int mf = 0; mf < 4; ++mf)
#pragma unroll
      for (int nf = 0; nf < 4; ++nf) {
        const int row = m0 + wr * 64 + mf * 16 + rr;
        const int col = nl + wc * 64 + nf * 16 + cc0;
        const float bv = bias[col];
#pragma unroll
        for (int r = 0; r < 4; ++r)
          dst[(size_t)(row + r) * HDIM + col] = __float2bfloat16((acc[mf][nf][r] + bv) * qs);
      }
  } else if (epi == 2) {
    bf16* dst = (bf16*)out;
#pragma unroll
    for (int mf = 0; mf < 4; ++mf)
#pragma unroll
      for (int nf = 0; nf < 4; ++nf) {
        const int row = m0 + wr * 64 + mf * 16 + rr;
        const int col = n0 + wc * 64 + nf * 16 + cc0;
        const float bv = b0[col];
#pragma unroll
        for (int r = 0; r < 4; ++r)
          dst[(size_t)(row + r) * N + col] = __float2bfloat16(gelu_f(acc[mf][nf][r] + bv));
      }
  } else {
    bf16* dst = (bf16*)out + (size_t)slice * 4718592;
#pragma unroll
    for (int mf = 0; mf < 4; ++mf)
#pragma unroll
      for (int nf = 0; nf < 4; ++nf) {
        const int row = m0 + wr * 64 + mf * 16 + rr;
        const int col = n0 + wc * 64 + nf * 16 + cc0;
        const float bv = slice ? 0.f : b0[col];
#pragma unroll
        for (int r = 0; r < 4; ++r)
          dst[(size_t)(row + r) * N + col] = __float2bfloat16(acc[mf][nf][r] + bv);
      }
  }
}

// ---------------- MFMA sliding-window attention (R12 exact — 67 µs best) ----------------
__global__ __launch_bounds__(256) void attn_mfma(
    const bf16* __restrict__ qkv, bf16* __restrict__ attb)
{
  const int c = blockIdx.x, h = blockIdx.y, b = blockIdx.z;
  __shared__ unsigned int Vtw[64 * 64];
  __shared__ __align__(16) bf16 Pl[4][32 * 40];
  const int t = threadIdx.x;
  const int lane = t & 63;
  const int w = t >> 6;
  const int fr = lane & 15;
  const int g = lane >> 4;
  const bf16* Km = qkv + (size_t)4718592;
  const bf16* Vm = qkv + (size_t)9437184;
  const size_t qrow0 = (size_t)(b * 768 + c * 128);

  bf16x8 qf[2][2];
#pragma unroll
  for (int nt = 0; nt < 2; ++nt)
#pragma unroll
    for (int ks = 0; ks < 2; ++ks)
      qf[nt][ks] = *(const bf16x8*)(qkv + (qrow0 + w * 32 + nt * 16 + fr) * HDIM + h * 64 + ks * 32 + g * 8);

  f32x4 oacc[4][2];
#pragma unroll
  for (int i = 0; i < 4; ++i) { oacc[i][0] = (f32x4)0.f; oacc[i][1] = (f32x4)0.f; }
  float mrun[2] = {-1e30f, -1e30f};
  float lrun[2] = {0.f, 0.f};

#pragma unroll 1
  for (int cc = c - 1; cc <= c + 1; ++cc) {
    if (cc < 0 || cc >= NCHUNK) continue;
    __syncthreads();
    {
      const int d0 = (t & 7) * 8;
#pragma unroll
      for (int half = 0; half < 2; ++half) {
        const int kp2 = (t >> 3) + half * 32;
        const bf16* vr = Vm + ((size_t)(b * 768 + cc * 128) + kp2 * 2) * HDIM + h * 64 + d0;
        uint4 r0 = *(const uint4*)vr;
        uint4 r1 = *(const uint4*)(vr + HDIM);
        unsigned int a0[4] = {r0.x, r0.y, r0.z, r0.w};
        unsigned int a1[4] = {r1.x, r1.y, r1.z, r1.w};
#pragma unroll
        for (int e = 0; e < 8; ++e) {
          const int d = d0 + e;
          unsigned int lo = (a0[e >> 1] >> ((e & 1) * 16)) & 0xffffu;
          unsigned int hi = (a1[e >> 1] >> ((e & 1) * 16)) & 0xffffu;
          unsigned int byteoff = (unsigned int)(d * 256 + kp2 * 4);
          byteoff ^= ((((d >> 3) ^ d) & 7) << 4);
          Vtw[byteoff >> 2] = lo | (hi << 16);
        }
      }
    }
    __syncthreads();
    const int mode = (cc < c) ? 0 : (cc == c ? 1 : 2);
    const bf16* Kc = Km + ((size_t)(b * 768 + cc * 128)) * HDIM + h * 64;

#pragma unroll 1
    for (int kb = 0; kb < 4; ++kb) {
      f32x4 sacc[2][2];
      sacc[0][0] = sacc[0][1] = sacc[1][0] = sacc[1][1] = (f32x4)0.f;
#pragma unroll
      for (int ks = 0; ks < 2; ++ks)
#pragma unroll
        for (int mt = 0; mt < 2; ++mt) {
          bf16x8 kf = *(const bf16x8*)(Kc + (size_t)(kb * 32 + mt * 16 + fr) * HDIM + ks * 32 + g * 8);
          sacc[mt][0] = __builtin_amdgcn_mfma_f32_16x16x32_bf16(kf, qf[0][ks], sacc[mt][0], 0, 0, 0);
          sacc[mt][1] = __builtin_amdgcn_mfma_f32_16x16x32_bf16(kf, qf[1][ks], sacc[mt][1], 0, 0, 0);
        }
#pragma unroll
      for (int nt = 0; nt < 2; ++nt) {
        const int iq = w * 32 + nt * 16 + fr;
        float pm = -1e30f;
#pragma unroll
        for (int mt = 0; mt < 2; ++mt)
#pragma unroll
          for (int r = 0; r < 4; ++r) {
            const int j = kb * 32 + mt * 16 + g * 4 + r;
            const bool valid = (mode == 1) || (mode == 0 ? (j >= iq) : (j <= iq));
            const float sv = valid ? sacc[mt][nt][r] : -1e30f;
            sacc[mt][nt][r] = sv;
            pm = fmaxf(pm, sv);
          }
        pm = fmaxf(pm, __shfl_xor(pm, 16));
        pm = fmaxf(pm, __shfl_xor(pm, 32));
        const float mnew = fmaxf(fmaxf(mrun[nt], pm), -1e20f);
        const float sc = __expf(mrun[nt] - mnew);
        mrun[nt] = mnew;
        lrun[nt] *= sc;
#pragma unroll
        for (int mt = 0; mt < 4; ++mt) oacc[mt][nt] *= sc;
        float ps = 0.f;
#pragma unroll
        for (int mt = 0; mt < 2; ++mt) {
          union { bf16 hh[4]; uint2 uu; } pk;
#pragma unroll
          for (int r = 0; r < 4; ++r) {
            const float p = __expf(sacc[mt][nt][r] - mnew);
            ps += p;
            pk.hh[r] = __float2bfloat16(p);
          }
          *(uint2*)(&Pl[w][(nt * 16 + fr) * 40 + mt * 16 + g * 4]) = pk.uu;
        }
        ps += __shfl_xor(ps, 16);
        ps += __shfl_xor(ps, 32);
        lrun[nt] += ps;
      }
      bf16x8 bpf[2];
#pragma unroll
      for (int nt = 0; nt < 2; ++nt)
        bpf[nt] = *(const bf16x8*)(&Pl[w][(nt * 16 + fr) * 40 + g * 8]);
#pragma unroll
      for (int mt = 0; mt < 4; ++mt) {
        const int d = mt * 16 + fr;
        unsigned int byteoff = (unsigned int)(d * 256 + kb * 64 + g * 16);
        byteoff ^= ((((d >> 3) ^ d) & 7) << 4);
        bf16x8 vf = *(const bf16x8*)((const char*)Vtw + byteoff);
        oacc[mt][0] = __builtin_amdgcn_mfma_f32_16x16x32_bf16(vf, bpf[0], oacc[mt][0], 0, 0, 0);
        oacc[mt][1] = __builtin_amdgcn_mfma_f32_16x16x32_bf16(vf, bpf[1], oacc[mt][1], 0, 0, 0);
      }
    }
  }
#pragma unroll
  for (int nt = 0; nt < 2; ++nt) {
    const float rl = 1.f / lrun[nt];
    bf16* orow = attb + (qrow0 + w * 32 + nt * 16 + fr) * HDIM + h * 64;
#pragma unroll
    for (int mt = 0; mt < 4; ++mt) {
      union { bf16 hh[4]; uint2 uu; } ok;
#pragma unroll
      for (int r = 0; r < 4; ++r) ok.hh[r] = __float2bfloat16(oacc[mt][nt][r] * rl);
      *(uint2*)(orow + mt * 16 + g * 4) = ok.uu;
    }
  }
}

// ---------------- LayerNorm kernels (bf16 residual stream) ----------------
__device__ __forceinline__ void blk_reduce2(float& s1, float& s2) {
#pragma unroll
  for (int o = 32; o > 0; o >>= 1) { s1 += __shfl_xor(s1, o); s2 += __shfl_xor(s2, o); }
  __shared__ float red[8];
  const int w = threadIdx.x >> 6;
  if ((threadIdx.x & 63) == 0) { red[w] = s1; red[4 + w] = s2; }
  __syncthreads();
  s1 = red[0] + red[1] + red[2] + red[3];
  s2 = red[4] + red[5] + red[6] + red[7];
}

__global__ __launch_bounds__(256) void embed_ln(
    const float* __restrict__ emb, const float* __restrict__ pos,
    const float* __restrict__ tte, const float* __restrict__ g,
    const float* __restrict__ bt, bf16* __restrict__ xb)
{
  const int row = blockIdx.x;
  const int s = row % 768;
  const int t = threadIdx.x;
  const size_t base = (size_t)row * HDIM;
  const size_t pbase = (size_t)(s + 2) * HDIM;
  float v[3];
#pragma unroll
  for (int i = 0; i < 3; ++i) {
    const int idx = t + i * 256;
    v[i] = emb[base + idx] + pos[pbase + idx] + tte[idx];
  }
  float s1 = v[0] + v[1] + v[2];
  float s2 = v[0]*v[0] + v[1]*v[1] + v[2]*v[2];
  blk_reduce2(s1, s2);
  const float mu = s1 * (1.f / 768.f);
  const float var = s2 * (1.f / 768.f) - mu * mu;
  const float inv = rsqrtf(var + 1e-12f);
#pragma unroll
  for (int i = 0; i < 3; ++i) {
    const int idx = t + i * 256;
    xb[base + idx] = __float2bfloat16((v[i] - mu) * inv * g[idx] + bt[idx]);
  }
}

__global__ __launch_bounds__(256) void add_ln(
    const bf16* __restrict__ tmp, bf16* __restrict__ xb,
    const float* __restrict__ g, const float* __restrict__ bt)
{
  const int row = blockIdx.x;
  const int t = threadIdx.x;
  const size_t base = (size_t)row * HDIM;
  float v[3];
#pragma unroll
  for (int i = 0; i < 3; ++i) {
    const int idx = t + i * 256;
    v[i] = __bfloat162float(xb[base + idx]) + __bfloat162float(tmp[base + idx]);
  }
  float s1 = v[0] + v[1] + v[2];
  float s2 = v[0]*v[0] + v[1]*v[1] + v[2]*v[2];
  blk_reduce2(s1, s2);
  const float mu = s1 * (1.f / 768.f);
  const float var = s2 * (1.f / 768.f) - mu * mu;
  const float inv = rsqrtf(var + 1e-12f);
#pragma unroll
  for (int i = 0; i < 3; ++i) {
    const int idx = t + i * 256;
    xb[base + idx] = __float2bfloat16((v[i] - mu) * inv * g[idx] + bt[idx]);
  }
}

__global__ __launch_bounds__(256) void add_ln2(
    const bf16* __restrict__ tmp0, const bf16* __restrict__ tmp1,
    bf16* __restrict__ xb,
    const float* __restrict__ g, const float* __restrict__ bt)
{
  const int row = blockIdx.x;
  const int t = threadIdx.x;
  const size_t base = (size_t)row * HDIM;
  float v[3];
#pragma unroll
  for (int i = 0; i < 3; ++i) {
    const int idx = t + i * 256;
    v[i] = __bfloat162float(xb[base + idx]) + __bfloat162float(tmp0[base + idx])
         + __bfloat162float(tmp1[base + idx]);
  }
  float s1 = v[0] + v[1] + v[2];
  float s2 = v[0]*v[0] + v[1]*v[1] + v[2]*v[2];
  blk_reduce2(s1, s2);
  const float mu = s1 * (1.f / 768.f);
  const float var = s2 * (1.f / 768.f) - mu * mu;
  const float inv = rsqrtf(var + 1e-12f);
#pragma unroll
  for (int i = 0; i < 3; ++i) {
    const int idx = t + i * 256;
    xb[base + idx] = __float2bfloat16((v[i] - mu) * inv * g[idx] + bt[idx]);
  }
}

__global__ __launch_bounds__(256) void add_ln2_last(
    const bf16* __restrict__ tmp0, const bf16* __restrict__ tmp1,
    const bf16* __restrict__ xb, float* __restrict__ xout,
    const float* __restrict__ g, const float* __restrict__ bt)
{
  const int row = blockIdx.x;
  const int t = threadIdx.x;
  const size_t base = (size_t)row * HDIM;
  float v[3];
#pragma unroll
  for (int i = 0; i < 3; ++i) {
    const int idx = t + i * 256;
    v[i] = __bfloat162float(xb[base + idx]) + __bfloat162float(tmp0[base + idx])
         + __bfloat162float(tmp1[base + idx]);
  }
  float s1 = v[0] + v[1] + v[2];
  float s2 = v[0]*v[0] + v[1]*v[1] + v[2]*v[2];
  blk_reduce2(s1, s2);
  const float mu = s1 * (1.f / 768.f);
  const float var = s2 * (1.f / 768.f) - mu * mu;
  const float inv = rsqrtf(var + 1e-12f);
#pragma unroll
  for (int i = 0; i < 3; ++i) {
    const int idx = t + i * 256;
    xout[base + idx] = (v[i] - mu) * inv * g[idx] + bt[idx];
  }
}

// ---------------- gate ----------------
__global__ __launch_bounds__(256) void gate_kernel(
    const float* __restrict__ x, const float* __restrict__ gw,
    const float* __restrict__ gb, float* __restrict__ out)
{
  const int row = blockIdx.x * 4 + (threadIdx.x >> 6);
  const int lane = threadIdx.x & 63;
  const float* xr = x + (size_t)row * HDIM;
  float s = 0.f;
#pragma unroll
  for (int i = 0; i < 12; ++i) s += xr[lane + i * 64] * gw[lane + i * 64];
#pragma unroll
  for (int o = 32; o > 0; o >>= 1) s += __shfl_xor(s, o);
  if (lane == 0) out[row] = s + gb[0];
}

// ---------------- host ----------------
extern "C" void kernel_launch(void* const* d_in, const int* in_sizes, int n_in,
                              void* d_out, int out_size, void* d_ws, size_t ws_size,
                              hipStream_t stream)
{
  const float* emb = (const float*)d_in[0];
  const float* pos = (const float*)d_in[2];
  const float* tte = (const float*)d_in[3];
  const float* eg  = (const float*)d_in[4];
  const float* eb  = (const float*)d_in[5];
  const float* Wq  = (const float*)d_in[6];
  const float* bq  = (const float*)d_in[7];
  const float* Wk  = (const float*)d_in[8];
  const float* bk  = (const float*)d_in[9];
  const float* Wv  = (const float*)d_in[10];
  const float* bv  = (const float*)d_in[11];
  const float* Wo  = (const float*)d_in[12];
  const float* bo  = (const float*)d_in[13];
  const float* g1  = (const float*)d_in[14];
  const float* be1 = (const float*)d_in[15];
  const float* Wi  = (const float*)d_in[16];
  const float* bi  = (const float*)d_in[17];
  const float* Wo2 = (const float*)d_in[18];
  const float* bo2 = (const float*)d_in[19];
  const float* g2  = (const float*)d_in[20];
  const float* be2 = (const float*)d_in[21];
  const float* gw  = (const float*)d_in[22];
  const float* gb  = (const float*)d_in[23];

  float* x   = (float*)d_out;        // f32 output (written only at final LN)
  float* gate = x + 4718592;
  char* wsp = (char*)d_ws;

  const size_t wtall_b = (size_t)12 * WTL * 2;
  const bool mega = ws_size >= wtall_b + 66060288;

  if (mega) {
    bf16* wt_all = (bf16*)wsp;
    bf16* xb   = (bf16*)(wsp + wtall_b);
    bf16* qkvb = (bf16*)(wsp + wtall_b + 9437184);
    bf16* tmp  = (bf16*)(wsp + wtall_b + 9437184 + 37748736);
    bf16* attb = qkvb + (size_t)3 * 4718592;
    bf16* ffb  = qkvb;

    embed_ln<<<6144, 256, 0, stream>>>(emb, pos, tte, eg, eb, xb);
    wconv_all<<<5184, 256, 0, stream>>>(Wq, Wk, Wv, Wo, Wi, Wo2, wt_all);

    for (int l = 0; l < 12; ++l) {
      bf16* wt = wt_all + (size_t)l * WTL;
      gemm128<<<864, 256, 0, stream>>>(xb, wt, qkvb,
          bq + l * 768, bk + l * 768, bv + l * 768, 18, 2304, 768, 24, 0, 1);
      attn_mfma<<<dim3(6, 12, 8), 256, 0, stream>>>(qkvb, attb);
      gemm128<<<288, 256, 0, stream>>>(attb, wt + 1769472, tmp,
          bo + l * 768, nullptr, nullptr, 6, 768, 768, 24, 3, 1);
      add_ln<<<6144, 256, 0, stream>>>(tmp, xb, g1 + l * 768, be1 + l * 768);
      gemm128<<<1152, 256, 0, stream>>>(xb, wt + 2359296, ffb,
          bi + l * 3072, nullptr, nullptr, 24, 3072, 768, 24, 2, 1);
      gemm128<<<576, 256, 0, stream>>>(ffb, wt + 4718592, tmp,
          bo2 + l * 768, nullptr, nullptr, 6, 768, 3072, 48, 3, 2);
      if (l < 11)
        add_ln2<<<6144, 256, 0, stream>>>(tmp, tmp + 4718592, xb, g2 + l * 768, be2 + l * 768);
      else
        add_ln2_last<<<6144, 256, 0, stream>>>(tmp, tmp + 4718592, xb, x, g2 + l * 768, be2 + l * 768);
    }
  } else {
    bf16* wt   = (bf16*)wsp;
    bf16* xb   = (bf16*)(wsp + 14155776);
    bf16* qkvb = (bf16*)(wsp + 23592960);
    bf16* tmp  = (bf16*)(wsp + 61341696);
    bf16* attb = qkvb + (size_t)3 * 4718592;
    bf16* ffb  = qkvb;

    embed_ln<<<6144, 256, 0, stream>>>(emb, pos, tte, eg, eb, xb);

    for (int l = 0; l < 12; ++l) {
      wconv<<<432, 256, 0, stream>>>(Wq + (size_t)l * 589824, Wk + (size_t)l * 589824,
                                     Wv + (size_t)l * 589824, Wo + (size_t)l * 589824,
                                     Wi + (size_t)l * 2359296, Wo2 + (size_t)l * 2359296, wt);
      gemm128<<<864, 256, 0, stream>>>(xb, wt, qkvb,
          bq + l * 768, bk + l * 768, bv + l * 768, 18, 2304, 768, 24, 0, 1);
      attn_mfma<<<dim3(6, 12, 8), 256, 0, stream>>>(qkvb, attb);
      gemm128<<<288, 256, 0, stream>>>(attb, wt + 1769472, tmp,
          bo + l * 768, nullptr, nullptr, 6, 768, 768, 24, 3, 1);
      add_ln<<<6144, 256, 0, stream>>>(tmp, xb, g1 + l * 768, be1 + l * 768);
      gemm128<<<1152, 256, 0, stream>>>(xb, wt + 2359296, ffb,
          bi + l * 3072, nullptr, nullptr, 24, 3072, 768, 24, 2, 1);
      gemm128<<<576, 256, 0, stream>>>(ffb, wt + 4718592, tmp,
          bo2 + l * 768, nullptr, nullptr, 6, 768, 3072, 48, 3, 2);
      if (l < 11)
        add_ln2<<<6144, 256, 0, stream>>>(tmp, tmp + 4718592, xb, g2 + l * 768, be2 + l * 768);
      else
        add_ln2_last<<<6144, 256, 0, stream>>>(tmp, tmp + 4718592, xb, x, g2 + l * 768, be2 + l * 768);
    }
  }

  gate_kernel<<<1536, 256, 0, stream>>>(x, gw, gb, gate);
}

// Round 23
// 2714.358 us; speedup vs baseline: 1.0083x; 1.0083x over previous
//
#include <hip/hip_runtime.h>
#include <hip/hip_bf16.h>
#include <math.h>
#include <stdint.h>

typedef __hip_bfloat16 bf16;
typedef __attribute__((ext_vector_type(8))) __bf16 bf16x8;
typedef __attribute__((ext_vector_type(4))) float f32x4;

#define HDIM 768
#define MROWS 6144
#define NCHUNK 6
#define WTL 7077888   // elements of transposed weights per layer

__device__ __forceinline__ float bf2f(unsigned int u) {
  union { unsigned int i; float f; } c; c.i = u << 16; return c.f;
}

__device__ __forceinline__ void gload16(const void* g, void* l) {
  __builtin_amdgcn_global_load_lds((const __attribute__((address_space(1))) void*)g,
                                   (__attribute__((address_space(3))) void*)l, 16, 0, 0);
}

// overflow-safe tanh-approx GELU (error ~1e-3 abs)
__device__ __forceinline__ float gelu_f(float v) {
  const float u2 = 1.5957691216057308f * (v + 0.044715f * v * v * v);
  const float e = __expf(u2);
  const float th = 1.f - 2.f / (e + 1.f);
  return 0.5f * v * (1.f + th);
}

// ---------------- weight transpose + f32->bf16 convert, 64x64 tiles (R21 best) ----
__device__ __forceinline__ void wconv_body64(
    int bid, const float* Wq, const float* Wk, const float* Wv, const float* Wo,
    const float* Wi, const float* Wo2, bf16* wt, float* tile /*[64*65]*/)
{
  const float* src; bf16* dst; int K, N, tIdx;
  if (bid < 576) {
    int m = bid / 144; tIdx = bid % 144; K = 768; N = 768;
    src = (m == 0) ? Wq : (m == 1) ? Wk : (m == 2) ? Wv : Wo;
    dst = wt + (size_t)m * 589824;
  } else if (bid < 1152) {
    tIdx = bid - 576; K = 768; N = 3072; src = Wi; dst = wt + 2359296;
  } else {
    tIdx = bid - 1152; K = 3072; N = 768; src = Wo2; dst = wt + 4718592;
  }
  const int tilesN = N >> 6;
  const int tn = tIdx % tilesN, tk = tIdx / tilesN;
  const int n0 = tn * 64, k0 = tk * 64;
  const int t = threadIdx.x;
  const int r0 = t >> 2, q = t & 3;

  const float* srow = src + (size_t)(k0 + r0) * N + n0 + q * 16;
#pragma unroll
  for (int j = 0; j < 4; ++j) {
    float4 v = *(const float4*)(srow + j * 4);
    float* tp = tile + r0 * 65 + q * 16 + j * 4;
    tp[0] = v.x; tp[1] = v.y; tp[2] = v.z; tp[3] = v.w;
  }
  __syncthreads();
  bf16* drow = dst + (size_t)(n0 + r0) * K + k0 + q * 16;
#pragma unroll
  for (int j = 0; j < 2; ++j) {
    union { bf16 h[8]; uint4 u; } pk;
#pragma unroll
    for (int e = 0; e < 8; ++e)
      pk.h[e] = __float2bfloat16(tile[(q * 16 + j * 8 + e) * 65 + r0]);
    *(uint4*)(drow + j * 8) = pk.u;
  }
}

__global__ __launch_bounds__(256) void wconv(
    const float* __restrict__ Wq, const float* __restrict__ Wk,
    const float* __restrict__ Wv, const float* __restrict__ Wo,
    const float* __restrict__ Wi, const float* __restrict__ Wo2,
    bf16* __restrict__ wt)
{
  __shared__ float tile[64 * 65];
  wconv_body64(blockIdx.x, Wq, Wk, Wv, Wo, Wi, Wo2, wt, tile);
}

__global__ __launch_bounds__(256) void wconv_all(
    const float* __restrict__ Wq, const float* __restrict__ Wk,
    const float* __restrict__ Wv, const float* __restrict__ Wo,
    const float* __restrict__ Wi, const float* __restrict__ Wo2,
    bf16* __restrict__ wt_all)
{
  __shared__ float tile[64 * 65];
  const int l = blockIdx.x / 1728;
  const int bid = blockIdx.x - l * 1728;
  wconv_body64(bid,
               Wq + (size_t)l * 589824, Wk + (size_t)l * 589824,
               Wv + (size_t)l * 589824, Wo + (size_t)l * 589824,
               Wi + (size_t)l * 2359296, Wo2 + (size_t)l * 2359296,
               wt_all + (size_t)l * WTL, tile);
}

// ---------------- GEMM 128x128, 4 waves, BK=32, ring-2 LDS (R12 exact — best) ----
__global__ __launch_bounds__(256, 3) void gemm128(
    const bf16* __restrict__ A, const bf16* __restrict__ Bt,
    void* __restrict__ out, const float* __restrict__ b0,
    const float* __restrict__ b1, const float* __restrict__ b2,
    int gx, int N, int K, int NT, int epi, int nslice)
{
  __shared__ __align__(16) bf16 As[2][4096];
  __shared__ __align__(16) bf16 Bs[2][4096];

  const int nwg = gridDim.x;
  const int wg = blockIdx.x;
  const int L = (wg & 7) * (nwg >> 3) + (wg >> 3);
  const int per = nwg / nslice;
  const int slice = L / per;
  const int Lr = L - slice * per;
  const int bx = Lr % gx, by = Lr / gx;
  const int m0 = by * 128, n0 = bx * 128;
  const int kb0 = slice * (NT << 5);

  const int t = threadIdx.x;
  const int lane = t & 63;
  const int w = t >> 6;
  const int wr = w >> 1, wc = w & 1;
  const int fr = lane & 15;
  const int g = lane >> 4;

  f32x4 acc[4][4];
#pragma unroll
  for (int i = 0; i < 4; ++i)
#pragma unroll
    for (int j = 0; j < 4; ++j) acc[i][j] = (f32x4)0.f;

  const int r0 = t >> 2, q0 = t & 3;
  const int sq = q0 ^ ((r0 >> 1) & 3);
  const bf16* gA0 = A + (size_t)(m0 + r0) * K + kb0 + sq * 8;
  const bf16* gB0 = Bt + (size_t)(n0 + r0) * K + kb0 + sq * 8;
  const int dst0 = t * 16;

  unsigned offA[4], offB[4];
#pragma unroll
  for (int mf = 0; mf < 4; ++mf) {
    const int R = wr * 64 + mf * 16 + fr;
    offA[mf] = (unsigned)((R * 64 + g * 16) ^ (((R >> 1) & 3) << 4));
  }
#pragma unroll
  for (int nf = 0; nf < 4; ++nf) {
    const int R = wc * 64 + nf * 16 + fr;
    offB[nf] = (unsigned)((R * 64 + g * 16) ^ (((R >> 1) & 3) << 4));
  }
  const unsigned ldsA = (unsigned)(uintptr_t)&As[0][0];
  const unsigned ldsB = (unsigned)(uintptr_t)&Bs[0][0];

#define STAGE(KT, RB) {                                                    \
    const bf16* a_ = gA0 + (size_t)(KT) * 32;                              \
    const bf16* b_ = gB0 + (size_t)(KT) * 32;                              \
    gload16(a_,                  (char*)As[RB] + dst0);                    \
    gload16(a_ + (size_t)64 * K, (char*)As[RB] + dst0 + 4096);             \
    gload16(b_,                  (char*)Bs[RB] + dst0);                    \
    gload16(b_ + (size_t)64 * K, (char*)Bs[RB] + dst0 + 4096); }

  STAGE(0, 0)

#define ITER(KT, CUR) {                                                    \
    const int pf_ = ((KT) + 1 < NT) ? (KT) + 1 : (KT);                     \
    STAGE(pf_, (CUR) ^ 1)                                                  \
    asm volatile("s_waitcnt vmcnt(4)" ::: "memory");                       \
    __builtin_amdgcn_s_barrier();                                          \
    bf16x8 af[4], bfr[4];                                                  \
    const unsigned baA_ = ldsA + (CUR) * 8192u;                            \
    const unsigned baB_ = ldsB + (CUR) * 8192u;                            \
    _Pragma("unroll")                                                      \
    for (int mf = 0; mf < 4; ++mf)                                         \
      asm volatile("ds_read_b128 %0, %1" : "=v"(af[mf]) : "v"(baA_ + offA[mf])); \
    _Pragma("unroll")                                                      \
    for (int nf = 0; nf < 4; ++nf)                                         \
      asm volatile("ds_read_b128 %0, %1" : "=v"(bfr[nf]) : "v"(baB_ + offB[nf])); \
    asm volatile("s_waitcnt lgkmcnt(0)" ::: "memory");                     \
    __builtin_amdgcn_sched_barrier(0);                                     \
    __builtin_amdgcn_s_barrier();                                          \
    __builtin_amdgcn_s_setprio(1);                                         \
    _Pragma("unroll")                                                      \
    for (int mf = 0; mf < 4; ++mf)                                         \
      _Pragma("unroll")                                                    \
      for (int nf = 0; nf < 4; ++nf)                                       \
        acc[mf][nf] = __builtin_amdgcn_mfma_f32_16x16x32_bf16(af[mf], bfr[nf], acc[mf][nf], 0, 0, 0); \
    __builtin_amdgcn_s_setprio(0);                                         \
  }

#pragma unroll 1
  for (int kt = 0; kt < NT; kt += 2) {
    ITER(kt, 0)
    ITER(kt + 1, 1)
  }
  asm volatile("s_waitcnt vmcnt(0)" ::: "memory");
#undef ITER
#undef STAGE

  const int rr = (lane >> 4) * 4;
  const int cc0 = lane & 15;
  if (epi == 0) {
    const int mat = n0 / HDIM;
    const float* bias = (mat == 0) ? b0 : (mat == 1) ? b1 : b2;
    const float qs = (mat == 0) ? 0.125f : 1.0f;
    bf16* dst = (bf16*)out + (size_t)mat * MROWS * HDIM;
    const int nl = n0 - mat * HDIM;
#pragma unroll
    for (int mf = 0; mf < 4; ++mf)
#pragma unroll
      for (int nf = 0; nf < 4; ++nf) {
        const int row = m0 + wr * 64 + mf * 16 + rr;
        const int col = nl + wc * 64 + nf * 16 + cc0;
        const float bv = bias[col];
#pragma unroll
        for (int r = 0; r < 4; ++r)
          dst[(size_t)(row + r) * HDIM + col] = __float2bfloat16((acc[mf][nf][r] + bv) * qs);
      }
  } else if (epi == 2) {
    bf16* dst = (bf16*)out;
#pragma unroll
    for (int mf = 0; mf < 4; ++mf)
#pragma unroll
      for (int nf = 0; nf < 4; ++nf) {
        const int row = m0 + wr * 64 + mf * 16 + rr;
        const int col = n0 + wc * 64 + nf * 16 + cc0;
        const float bv = b0[col];
#pragma unroll
        for (int r = 0; r < 4; ++r)
          dst[(size_t)(row + r) * N + col] = __float2bfloat16(gelu_f(acc[mf][nf][r] + bv));
      }
  } else {
    bf16* dst = (bf16*)out + (size_t)slice * 4718592;
#pragma unroll
    for (int mf = 0; mf < 4; ++mf)
#pragma unroll
      for (int nf = 0; nf < 4; ++nf) {
        const int row = m0 + wr * 64 + mf * 16 + rr;
        const int col = n0 + wc * 64 + nf * 16 + cc0;
        const float bv = slice ? 0.f : b0[col];
#pragma unroll
        for (int r = 0; r < 4; ++r)
          dst[(size_t)(row + r) * N + col] = __float2bfloat16(acc[mf][nf][r] + bv);
      }
  }
}

// ---------------- MFMA sliding-window attention (R12 exact — 67 µs best) ----------------
__global__ __launch_bounds__(256) void attn_mfma(
    const bf16* __restrict__ qkv, bf16* __restrict__ attb)
{
  const int c = blockIdx.x, h = blockIdx.y, b = blockIdx.z;
  __shared__ unsigned int Vtw[64 * 64];
  __shared__ __align__(16) bf16 Pl[4][32 * 40];
  const int t = threadIdx.x;
  const int lane = t & 63;
  const int w = t >> 6;
  const int fr = lane & 15;
  const int g = lane >> 4;
  const bf16* Km = qkv + (size_t)4718592;
  const bf16* Vm = qkv + (size_t)9437184;
  const size_t qrow0 = (size_t)(b * 768 + c * 128);

  bf16x8 qf[2][2];
#pragma unroll
  for (int nt = 0; nt < 2; ++nt)
#pragma unroll
    for (int ks = 0; ks < 2; ++ks)
      qf[nt][ks] = *(const bf16x8*)(qkv + (qrow0 + w * 32 + nt * 16 + fr) * HDIM + h * 64 + ks * 32 + g * 8);

  f32x4 oacc[4][2];
#pragma unroll
  for (int i = 0; i < 4; ++i) { oacc[i][0] = (f32x4)0.f; oacc[i][1] = (f32x4)0.f; }
  float mrun[2] = {-1e30f, -1e30f};
  float lrun[2] = {0.f, 0.f};

#pragma unroll 1
  for (int cc = c - 1; cc <= c + 1; ++cc) {
    if (cc < 0 || cc >= NCHUNK) continue;
    __syncthreads();
    {
      const int d0 = (t & 7) * 8;
#pragma unroll
      for (int half = 0; half < 2; ++half) {
        const int kp2 = (t >> 3) + half * 32;
        const bf16* vr = Vm + ((size_t)(b * 768 + cc * 128) + kp2 * 2) * HDIM + h * 64 + d0;
        uint4 r0 = *(const uint4*)vr;
        uint4 r1 = *(const uint4*)(vr + HDIM);
        unsigned int a0[4] = {r0.x, r0.y, r0.z, r0.w};
        unsigned int a1[4] = {r1.x, r1.y, r1.z, r1.w};
#pragma unroll
        for (int e = 0; e < 8; ++e) {
          const int d = d0 + e;
          unsigned int lo = (a0[e >> 1] >> ((e & 1) * 16)) & 0xffffu;
          unsigned int hi = (a1[e >> 1] >> ((e & 1) * 16)) & 0xffffu;
          unsigned int byteoff = (unsigned int)(d * 256 + kp2 * 4);
          byteoff ^= ((((d >> 3) ^ d) & 7) << 4);
          Vtw[byteoff >> 2] = lo | (hi << 16);
        }
      }
    }
    __syncthreads();
    const int mode = (cc < c) ? 0 : (cc == c ? 1 : 2);
    const bf16* Kc = Km + ((size_t)(b * 768 + cc * 128)) * HDIM + h * 64;

#pragma unroll 1
    for (int kb = 0; kb < 4; ++kb) {
      f32x4 sacc[2][2];
      sacc[0][0] = sacc[0][1] = sacc[1][0] = sacc[1][1] = (f32x4)0.f;
#pragma unroll
      for (int ks = 0; ks < 2; ++ks)
#pragma unroll
        for (int mt = 0; mt < 2; ++mt) {
          bf16x8 kf = *(const bf16x8*)(Kc + (size_t)(kb * 32 + mt * 16 + fr) * HDIM + ks * 32 + g * 8);
          sacc[mt][0] = __builtin_amdgcn_mfma_f32_16x16x32_bf16(kf, qf[0][ks], sacc[mt][0], 0, 0, 0);
          sacc[mt][1] = __builtin_amdgcn_mfma_f32_16x16x32_bf16(kf, qf[1][ks], sacc[mt][1], 0, 0, 0);
        }
#pragma unroll
      for (int nt = 0; nt < 2; ++nt) {
        const int iq = w * 32 + nt * 16 + fr;
        float pm = -1e30f;
#pragma unroll
        for (int mt = 0; mt < 2; ++mt)
#pragma unroll
          for (int r = 0; r < 4; ++r) {
            const int j = kb * 32 + mt * 16 + g * 4 + r;
            const bool valid = (mode == 1) || (mode == 0 ? (j >= iq) : (j <= iq));
            const float sv = valid ? sacc[mt][nt][r] : -1e30f;
            sacc[mt][nt][r] = sv;
            pm = fmaxf(pm, sv);
          }
        pm = fmaxf(pm, __shfl_xor(pm, 16));
        pm = fmaxf(pm, __shfl_xor(pm, 32));
        const float mnew = fmaxf(fmaxf(mrun[nt], pm), -1e20f);
        const float sc = __expf(mrun[nt] - mnew);
        mrun[nt] = mnew;
        lrun[nt] *= sc;
#pragma unroll
        for (int mt = 0; mt < 4; ++mt) oacc[mt][nt] *= sc;
        float ps = 0.f;
#pragma unroll
        for (int mt = 0; mt < 2; ++mt) {
          union { bf16 hh[4]; uint2 uu; } pk;
#pragma unroll
          for (int r = 0; r < 4; ++r) {
            const float p = __expf(sacc[mt][nt][r] - mnew);
            ps += p;
            pk.hh[r] = __float2bfloat16(p);
          }
          *(uint2*)(&Pl[w][(nt * 16 + fr) * 40 + mt * 16 + g * 4]) = pk.uu;
        }
        ps += __shfl_xor(ps, 16);
        ps += __shfl_xor(ps, 32);
        lrun[nt] += ps;
      }
      bf16x8 bpf[2];
#pragma unroll
      for (int nt = 0; nt < 2; ++nt)
        bpf[nt] = *(const bf16x8*)(&Pl[w][(nt * 16 + fr) * 40 + g * 8]);
#pragma unroll
      for (int mt = 0; mt < 4; ++mt) {
        const int d = mt * 16 + fr;
        unsigned int byteoff = (unsigned int)(d * 256 + kb * 64 + g * 16);
        byteoff ^= ((((d >> 3) ^ d) & 7) << 4);
        bf16x8 vf = *(const bf16x8*)((const char*)Vtw + byteoff);
        oacc[mt][0] = __builtin_amdgcn_mfma_f32_16x16x32_bf16(vf, bpf[0], oacc[mt][0], 0, 0, 0);
        oacc[mt][1] = __builtin_amdgcn_mfma_f32_16x16x32_bf16(vf, bpf[1], oacc[mt][1], 0, 0, 0);
      }
    }
  }
#pragma unroll
  for (int nt = 0; nt < 2; ++nt) {
    const float rl = 1.f / lrun[nt];
    bf16* orow = attb + (qrow0 + w * 32 + nt * 16 + fr) * HDIM + h * 64;
#pragma unroll
    for (int mt = 0; mt < 4; ++mt) {
      union { bf16 hh[4]; uint2 uu; } ok;
#pragma unroll
      for (int r = 0; r < 4; ++r) ok.hh[r] = __float2bfloat16(oacc[mt][nt][r] * rl);
      *(uint2*)(orow + mt * 16 + g * 4) = ok.uu;
    }
  }
}

// ---------------- LayerNorm kernels (bf16 residual stream) ----------------
__device__ __forceinline__ void blk_reduce2(float& s1, float& s2) {
#pragma unroll
  for (int o = 32; o > 0; o >>= 1) { s1 += __shfl_xor(s1, o); s2 += __shfl_xor(s2, o); }
  __shared__ float red[8];
  const int w = threadIdx.x >> 6;
  if ((threadIdx.x & 63) == 0) { red[w] = s1; red[4 + w] = s2; }
  __syncthreads();
  s1 = red[0] + red[1] + red[2] + red[3];
  s2 = red[4] + red[5] + red[6] + red[7];
}

__global__ __launch_bounds__(256) void embed_ln(
    const float* __restrict__ emb, const float* __restrict__ pos,
    const float* __restrict__ tte, const float* __restrict__ g,
    const float* __restrict__ bt, bf16* __restrict__ xb)
{
  const int row = blockIdx.x;
  const int s = row % 768;
  const int t = threadIdx.x;
  const size_t base = (size_t)row * HDIM;
  const size_t pbase = (size_t)(s + 2) * HDIM;
  float v[3];
#pragma unroll
  for (int i = 0; i < 3; ++i) {
    const int idx = t + i * 256;
    v[i] = emb[base + idx] + pos[pbase + idx] + tte[idx];
  }
  float s1 = v[0] + v[1] + v[2];
  float s2 = v[0]*v[0] + v[1]*v[1] + v[2]*v[2];
  blk_reduce2(s1, s2);
  const float mu = s1 * (1.f / 768.f);
  const float var = s2 * (1.f / 768.f) - mu * mu;
  const float inv = rsqrtf(var + 1e-12f);
#pragma unroll
  for (int i = 0; i < 3; ++i) {
    const int idx = t + i * 256;
    xb[base + idx] = __float2bfloat16((v[i] - mu) * inv * g[idx] + bt[idx]);
  }
}

__global__ __launch_bounds__(256) void add_ln(
    const bf16* __restrict__ tmp, bf16* __restrict__ xb,
    const float* __restrict__ g, const float* __restrict__ bt)
{
  const int row = blockIdx.x;
  const int t = threadIdx.x;
  const size_t base = (size_t)row * HDIM;
  float v[3];
#pragma unroll
  for (int i = 0; i < 3; ++i) {
    const int idx = t + i * 256;
    v[i] = __bfloat162float(xb[base + idx]) + __bfloat162float(tmp[base + idx]);
  }
  float s1 = v[0] + v[1] + v[2];
  float s2 = v[0]*v[0] + v[1]*v[1] + v[2]*v[2];
  blk_reduce2(s1, s2);
  const float mu = s1 * (1.f / 768.f);
  const float var = s2 * (1.f / 768.f) - mu * mu;
  const float inv = rsqrtf(var + 1e-12f);
#pragma unroll
  for (int i = 0; i < 3; ++i) {
    const int idx = t + i * 256;
    xb[base + idx] = __float2bfloat16((v[i] - mu) * inv * g[idx] + bt[idx]);
  }
}

__global__ __launch_bounds__(256) void add_ln2(
    const bf16* __restrict__ tmp0, const bf16* __restrict__ tmp1,
    bf16* __restrict__ xb,
    const float* __restrict__ g, const float* __restrict__ bt)
{
  const int row = blockIdx.x;
  const int t = threadIdx.x;
  const size_t base = (size_t)row * HDIM;
  float v[3];
#pragma unroll
  for (int i = 0; i < 3; ++i) {
    const int idx = t + i * 256;
    v[i] = __bfloat162float(xb[base + idx]) + __bfloat162float(tmp0[base + idx])
         + __bfloat162float(tmp1[base + idx]);
  }
  float s1 = v[0] + v[1] + v[2];
  float s2 = v[0]*v[0] + v[1]*v[1] + v[2]*v[2];
  blk_reduce2(s1, s2);
  const float mu = s1 * (1.f / 768.f);
  const float var = s2 * (1.f / 768.f) - mu * mu;
  const float inv = rsqrtf(var + 1e-12f);
#pragma unroll
  for (int i = 0; i < 3; ++i) {
    const int idx = t + i * 256;
    xb[base + idx] = __float2bfloat16((v[i] - mu) * inv * g[idx] + bt[idx]);
  }
}

__global__ __launch_bounds__(256) void add_ln2_last(
    const bf16* __restrict__ tmp0, const bf16* __restrict__ tmp1,
    const bf16* __restrict__ xb, float* __restrict__ xout,
    const float* __restrict__ g, const float* __restrict__ bt)
{
  const int row = blockIdx.x;
  const int t = threadIdx.x;
  const size_t base = (size_t)row * HDIM;
  float v[3];
#pragma unroll
  for (int i = 0; i < 3; ++i) {
    const int idx = t + i * 256;
    v[i] = __bfloat162float(xb[base + idx]) + __bfloat162float(tmp0[base + idx])
         + __bfloat162float(tmp1[base + idx]);
  }
  float s1 = v[0] + v[1] + v[2];
  float s2 = v[0]*v[0] + v[1]*v[1] + v[2]*v[2];
  blk_reduce2(s1, s2);
  const float mu = s1 * (1.f / 768.f);
  const float var = s2 * (1.f / 768.f) - mu * mu;
  const float inv = rsqrtf(var + 1e-12f);
#pragma unroll
  for (int i = 0; i < 3; ++i) {
    const int idx = t + i * 256;
    xout[base + idx] = (v[i] - mu) * inv * g[idx] + bt[idx];
  }
}

// ---------------- gate ----------------
__global__ __launch_bounds__(256) void gate_kernel(
    const float* __restrict__ x, const float* __restrict__ gw,
    const float* __restrict__ gb, float* __restrict__ out)
{
  const int row = blockIdx.x * 4 + (threadIdx.x >> 6);
  const int lane = threadIdx.x & 63;
  const float* xr = x + (size_t)row * HDIM;
  float s = 0.f;
#pragma unroll
  for (int i = 0; i < 12; ++i) s += xr[lane + i * 64] * gw[lane + i * 64];
#pragma unroll
  for (int o = 32; o > 0; o >>= 1) s += __shfl_xor(s, o);
  if (lane == 0) out[row] = s + gb[0];
}

// ---------------- host ----------------
extern "C" void kernel_launch(void* const* d_in, const int* in_sizes, int n_in,
                              void* d_out, int out_size, void* d_ws, size_t ws_size,
                              hipStream_t stream)
{
  const float* emb = (const float*)d_in[0];
  const float* pos = (const float*)d_in[2];
  const float* tte = (const float*)d_in[3];
  const float* eg  = (const float*)d_in[4];
  const float* eb  = (const float*)d_in[5];
  const float* Wq  = (const float*)d_in[6];
  const float* bq  = (const float*)d_in[7];
  const float* Wk  = (const float*)d_in[8];
  const float* bk  = (const float*)d_in[9];
  const float* Wv  = (const float*)d_in[10];
  const float* bv  = (const float*)d_in[11];
  const float* Wo  = (const float*)d_in[12];
  const float* bo  = (const float*)d_in[13];
  const float* g1  = (const float*)d_in[14];
  const float* be1 = (const float*)d_in[15];
  const float* Wi  = (const float*)d_in[16];
  const float* bi  = (const float*)d_in[17];
  const float* Wo2 = (const float*)d_in[18];
  const float* bo2 = (const float*)d_in[19];
  const float* g2  = (const float*)d_in[20];
  const float* be2 = (const float*)d_in[21];
  const float* gw  = (const float*)d_in[22];
  const float* gb  = (const float*)d_in[23];

  float* x   = (float*)d_out;        // f32 output (written only at final LN)
  float* gate = x + 4718592;
  char* wsp = (char*)d_ws;

  const size_t wtall_b = (size_t)12 * WTL * 2;
  const bool mega = ws_size >= wtall_b + 66060288;

  if (mega) {
    bf16* wt_all = (bf16*)wsp;
    bf16* xb   = (bf16*)(wsp + wtall_b);
    bf16* qkvb = (bf16*)(wsp + wtall_b + 9437184);
    bf16* tmp  = (bf16*)(wsp + wtall_b + 9437184 + 37748736);
    bf16* attb = qkvb + (size_t)3 * 4718592;
    bf16* ffb  = qkvb;

    embed_ln<<<6144, 256, 0, stream>>>(emb, pos, tte, eg, eb, xb);
    wconv_all<<<20736, 256, 0, stream>>>(Wq, Wk, Wv, Wo, Wi, Wo2, wt_all);

    for (int l = 0; l < 12; ++l) {
      bf16* wt = wt_all + (size_t)l * WTL;
      gemm128<<<864, 256, 0, stream>>>(xb, wt, qkvb,
          bq + l * 768, bk + l * 768, bv + l * 768, 18, 2304, 768, 24, 0, 1);
      attn_mfma<<<dim3(6, 12, 8), 256, 0, stream>>>(qkvb, attb);
      gemm128<<<288, 256, 0, stream>>>(attb, wt + 1769472, tmp,
          bo + l * 768, nullptr, nullptr, 6, 768, 768, 24, 3, 1);
      add_ln<<<6144, 256, 0, stream>>>(tmp, xb, g1 + l * 768, be1 + l * 768);
      gemm128<<<1152, 256, 0, stream>>>(xb, wt + 2359296, ffb,
          bi + l * 3072, nullptr, nullptr, 24, 3072, 768, 24, 2, 1);
      gemm128<<<576, 256, 0, stream>>>(ffb, wt + 4718592, tmp,
          bo2 + l * 768, nullptr, nullptr, 6, 768, 3072, 48, 3, 2);
      if (l < 11)
        add_ln2<<<6144, 256, 0, stream>>>(tmp, tmp + 4718592, xb, g2 + l * 768, be2 + l * 768);
      else
        add_ln2_last<<<6144, 256, 0, stream>>>(tmp, tmp + 4718592, xb, x, g2 + l * 768, be2 + l * 768);
    }
  } else {
    bf16* wt   = (bf16*)wsp;
    bf16* xb   = (bf16*)(wsp + 14155776);
    bf16* qkvb = (bf16*)(wsp + 23592960);
    bf16* tmp  = (bf16*)(wsp + 61341696);
    bf16* attb = qkvb + (size_t)3 * 4718592;
    bf16* ffb  = qkvb;

    embed_ln<<<6144, 256, 0, stream>>>(emb, pos, tte, eg, eb, xb);

    for (int l = 0; l < 12; ++l) {
      wconv<<<1728, 256, 0, stream>>>(Wq + (size_t)l * 589824, Wk + (size_t)l * 589824,
                                      Wv + (size_t)l * 589824, Wo + (size_t)l * 589824,
                                      Wi + (size_t)l * 2359296, Wo2 + (size_t)l * 2359296, wt);
      gemm128<<<864, 256, 0, stream>>>(xb, wt, qkvb,
          bq + l * 768, bk + l * 768, bv + l * 768, 18, 2304, 768, 24, 0, 1);
      attn_mfma<<<dim3(6, 12, 8), 256, 0, stream>>>(qkvb, attb);
      gemm128<<<288, 256, 0, stream>>>(attb, wt + 1769472, tmp,
          bo + l * 768, nullptr, nullptr, 6, 768, 768, 24, 3, 1);
      add_ln<<<6144, 256, 0, stream>>>(tmp, xb, g1 + l * 768, be1 + l * 768);
      gemm128<<<1152, 256, 0, stream>>>(xb, wt + 2359296, ffb,
          bi + l * 3072, nullptr, nullptr, 24, 3072, 768, 24, 2, 1);
      gemm128<<<576, 256, 0, stream>>>(ffb, wt + 4718592, tmp,
          bo2 + l * 768, nullptr, nullptr, 6, 768, 3072, 48, 3, 2);
      if (l < 11)
        add_ln2<<<6144, 256, 0, stream>>>(tmp, tmp + 4718592, xb, g2 + l * 768, be2 + l * 768);
      else
        add_ln2_last<<<6144, 256, 0, stream>>>(tmp, tmp + 4718592, xb, x, g2 + l * 768, be2 + l * 768);
    }
  }

  gate_kernel<<<1536, 256, 0, stream>>>(x, gw, gb, gate);
}